// Round 2
// baseline (160.050 us; speedup 1.0000x reference)
//
#include <hip/hip_runtime.h>
#include <stdint.h>

#define Cc 128

typedef __attribute__((ext_vector_type(4))) float f32x4;
typedef __attribute__((ext_vector_type(8))) short s16x8;

__device__ __forceinline__ unsigned int asu(float f) { union { float f; unsigned int u; } v; v.f = f; return v.u; }
__device__ __forceinline__ float asf(unsigned int u) { union { unsigned int u; float f; } v; v.u = u; return v.f; }

__device__ __forceinline__ unsigned short f2bf_rne(float f) {
  unsigned int u = asu(f);
  unsigned int r = u + 0x7FFFu + ((u >> 16) & 1u);
  return (unsigned short)(r >> 16);
}

// pack two f32 -> bf16x2 dword (round-half-up via +0x8000, take high16)
__device__ __forceinline__ unsigned int pk2(float lo, float hi) {
  return __builtin_amdgcn_perm(asu(hi) + 0x8000u, asu(lo) + 0x8000u, 0x07060302u);
}

// one dword of packed bf16 pairs from A and B: relu(a+b) per half, repack
__device__ __forceinline__ unsigned int cvt1(unsigned int a, unsigned int b) {
  float alo = asf(a << 16), ahi = asf(a & 0xFFFF0000u);
  float blo = asf(b << 16), bhi = asf(b & 0xFFFF0000u);
  float lo = fmaxf(alo + blo, 0.f);
  float hi = fmaxf(ahi + bhi, 0.f);
  return pk2(lo, hi);
}

#define MFMA16(a, b, c) __builtin_amdgcn_mfma_f32_16x16x32_bf16((a), (b), (c), 0, 0, 0)

// ---------------------------------------------------------------------------
// pack_kernel: weights -> MFMA-fragment-major bf16; plus t3/u3 constants.
// Fragment (kt, ct, lane l, elem j) <- W[kt*32 + (l>>4)*8 + j][ct*16 + (l&15)]
// ---------------------------------------------------------------------------
__global__ void pack_kernel(const float* __restrict__ W1,
                            const float* __restrict__ W2,
                            const float* __restrict__ W3,
                            const float* __restrict__ b2,
                            const float* __restrict__ b3,
                            unsigned short* __restrict__ W1p,
                            unsigned short* __restrict__ W2p,
                            unsigned short* __restrict__ W3p,
                            float* __restrict__ t3v,
                            float* __restrict__ u3v) {
  int blk = blockIdx.x, t = threadIdx.x;
  if (blk < 32) {
    // W1p: K=128, 512 packed cols (0..255 = W1_top out-cols, 256..511 = W1_bot)
    int f = blk * 256 + t;
    int l = f & 63, ct = (f >> 6) & 31, kt = f >> 11;
    int col = ct * 16 + (l & 15);
    int k0 = kt * 32 + ((l >> 4) << 3);
    unsigned short tmp[8];
#pragma unroll
    for (int j = 0; j < 8; ++j) {
      int k = k0 + j;
      float v = (col < 256) ? W1[k * 256 + col] : W1[(128 + k) * 256 + (col - 256)];
      tmp[j] = f2bf_rne(v);
    }
    *(uint4*)(W1p + f * 8) = *(uint4*)tmp;
  } else if (blk < 64) {
    // W2p: 256x256
    int f = (blk - 32) * 256 + t;
    int l = f & 63, ct = (f >> 6) & 15, kt = f >> 10;
    int col = ct * 16 + (l & 15);
    int k0 = kt * 32 + ((l >> 4) << 3);
    unsigned short tmp[8];
#pragma unroll
    for (int j = 0; j < 8; ++j) tmp[j] = f2bf_rne(W2[(k0 + j) * 256 + col]);
    *(uint4*)(W2p + f * 8) = *(uint4*)tmp;
  } else if (blk < 80) {
    // W3p: 256x128
    int f = (blk - 64) * 256 + t;
    int l = f & 63, ct = (f >> 6) & 7, kt = f >> 9;
    int col = ct * 16 + (l & 15);
    int k0 = kt * 32 + ((l >> 4) << 3);
    unsigned short tmp[8];
#pragma unroll
    for (int j = 0; j < 8; ++j) tmp[j] = f2bf_rne(W3[(k0 + j) * 128 + col]);
    *(uint4*)(W3p + f * 8) = *(uint4*)tmp;
  } else {
    // t3 = b3 + c3, u3 = 16*c3 with c3 = relu(b2) @ W3
    if (t < 128) {
      float s = 0.f;
      for (int j = 0; j < 256; ++j) s += fmaxf(b2[j], 0.f) * W3[j * 128 + t];
      t3v[t] = b3[t] + s;
      u3v[t] = 16.f * s;
    }
  }
}

// ---------------------------------------------------------------------------
// k1: per-node  A = feats@W1_top + b1  (cols 0..255),  Bc = feats@W1_bot.
// Reads f32 feats directly (convert in-register). Epilogue: LDS transpose
// (XOR-swizzled) -> fully coalesced 16B global stores.
// ---------------------------------------------------------------------------
__global__ __launch_bounds__(256, 2) void k1_gemm(
    const float* __restrict__ feats,
    const unsigned short* __restrict__ W1p,
    const float* __restrict__ b1,
    unsigned short* __restrict__ A_ws,
    unsigned short* __restrict__ B_ws) {
  __shared__ __attribute__((aligned(16))) unsigned short cs[64 * 512];  // 64KB
  char* cb = (char*)cs;
  int m0 = blockIdx.x * 64;
  int t = threadIdx.x, w = t >> 6, l = t & 63, lr = l & 15, lg = l >> 4;
  f32x4 zero4 = {0.f, 0.f, 0.f, 0.f};
  f32x4 acc[4][8];
#pragma unroll
  for (int i = 0; i < 4; ++i)
#pragma unroll
    for (int j = 0; j < 8; ++j) acc[i][j] = zero4;

  for (int kt = 0; kt < 4; ++kt) {
    s16x8 a[4];
#pragma unroll
    for (int rt = 0; rt < 4; ++rt) {
      const float* fr = feats + (m0 + rt * 16 + lr) * 128 + kt * 32 + lg * 8;
      float4 f0 = *(const float4*)fr;
      float4 f1 = *(const float4*)(fr + 4);
      uint4 pk;
      pk.x = pk2(f0.x, f0.y);
      pk.y = pk2(f0.z, f0.w);
      pk.z = pk2(f1.x, f1.y);
      pk.w = pk2(f1.z, f1.w);
      *(uint4*)&a[rt] = pk;
    }
#pragma unroll
    for (int ctl = 0; ctl < 8; ++ctl) {
      s16x8 bf = *(const s16x8*)(W1p + (((kt * 32) + (w * 8 + ctl)) * 64 + l) * 8);
#pragma unroll
      for (int rt = 0; rt < 4; ++rt)
        acc[rt][ctl] = MFMA16(a[rt], bf, acc[rt][ctl]);
    }
  }

  // epilogue -> LDS [node 0..63][ch 0..511] bf16, XOR-swizzled 16B chunks
#pragma unroll
  for (int ctl = 0; ctl < 8; ++ctl) {
    int col = w * 128 + ctl * 16 + lr;
    float bias = (col < 256) ? b1[col] : 0.f;
#pragma unroll
    for (int rt = 0; rt < 4; ++rt) {
#pragma unroll
      for (int reg = 0; reg < 4; ++reg) {
        int node = rt * 16 + lg * 4 + reg;
        float v = acc[rt][ctl][reg] + bias;
        unsigned short bv = (unsigned short)((asu(v) + 0x8000u) >> 16);
        *(unsigned short*)(cb + ((node * 1024 + col * 2) ^ ((node & 7) << 4))) = bv;
      }
    }
  }
  __syncthreads();
  // store: per wave one row per i; lane l -> cols [8l, 8l+8)
#pragma unroll
  for (int i = 0; i < 16; ++i) {
    int row = i * 4 + w;
    uint4 v = *(const uint4*)(cb + row * 1024 + ((l * 16) ^ ((row & 7) << 4)));
    int node = m0 + row;
    unsigned short* dst = (l < 32) ? (A_ws + node * 256 + l * 8)
                                   : (B_ws + node * 256 + (l - 32) * 8);
    *(uint4*)dst = v;
  }
}

// ---------------------------------------------------------------------------
// k2: fused edge MLP. wg = 8 queries x 16 neighbors = 128 edge-rows,
// 512 threads (8 waves), K-split into two 128-col phases over one 32KB LDS
// buffer. Mask folded into h1 staging; analytic correction in final epilogue.
// ---------------------------------------------------------------------------
__global__ __launch_bounds__(512, 4) void k2_fused(
    const unsigned short* __restrict__ A_ws,
    const unsigned short* __restrict__ B_ws,
    const unsigned short* __restrict__ W2p,
    const unsigned short* __restrict__ W3p,
    const int* __restrict__ n_idxs,
    const int* __restrict__ valid,
    const float* __restrict__ b2,
    const float* __restrict__ t3v,
    const float* __restrict__ u3v,
    float* __restrict__ out) {
  __shared__ __attribute__((aligned(16))) unsigned short h1s[128 * 128];  // 32KB phase buf
  __shared__ __attribute__((aligned(16))) unsigned short gs[16 * 264];    // 8.25KB
  __shared__ float nvf[8];
  char* h1b = (char*)h1s;
  char* gb = (char*)gs;

  int t = threadIdx.x;
  int w = t >> 6, l = t & 63, lr = l & 15, lg = l >> 4;
  int wg = blockIdx.x;
  int qbase = wg * 8, ebase = wg * 128;
  int bN = qbase & ~4095;  // batch*N

  // zero gs rows 8..15 (cols 0..255) so GEMM3's 16-row fragment is clean
  if (t < 256) {
    int row = 8 + (t >> 5), ch = t & 31;
    *(f32x4*)(gb + row * 528 + ch * 16) = f32x4{0.f, 0.f, 0.f, 0.f};
  }
  if (t < 8) {
    int s = 0;
#pragma unroll
    for (int k = 0; k < 16; ++k) s += valid[ebase + t * 16 + k];
    nvf[t] = (float)s;
  }

  // staging assignment: thread t -> edge row r = t>>2, quarter sub = t&3
  int r = t >> 2, sub = t & 3;
  int nb = n_idxs[ebase + r];
  bool vld = valid[ebase + r] != 0;
  const unsigned short* pa = A_ws + (qbase + (r >> 4)) * 256 + sub * 32;
  const unsigned short* pb = B_ws + (bN + nb) * 256 + sub * 32;
  int wbase = r * 256 + sub * 64;
  int swz = (r & 7) << 4;
  int rswz = (lr & 7) << 4;

  f32x4 zero4 = {0.f, 0.f, 0.f, 0.f};
  f32x4 acc[8][2];
#pragma unroll
  for (int i = 0; i < 8; ++i) {
    acc[i][0] = zero4;
    acc[i][1] = zero4;
  }

  for (int p = 0; p < 2; ++p) {
    // ---- stage phase p: h1[128 rows][128 cols] = relu(A+B), masked ----
#pragma unroll
    for (int i = 0; i < 4; ++i) {
      uint4 av = *(const uint4*)(pa + p * 128 + i * 8);
      uint4 bv = *(const uint4*)(pb + p * 128 + i * 8);
      uint4 o;
      o.x = cvt1(av.x, bv.x);
      o.y = cvt1(av.y, bv.y);
      o.z = cvt1(av.z, bv.z);
      o.w = cvt1(av.w, bv.w);
      if (!vld) { o.x = 0u; o.y = 0u; o.z = 0u; o.w = 0u; }
      *(uint4*)(h1b + ((wbase + i * 16) ^ swz)) = o;
    }
    __syncthreads();
    // ---- GEMM over this K-half; wave w -> cols [w*32, w*32+32) ----
#pragma unroll
    for (int kt = 0; kt < 4; ++kt) {
      s16x8 a[8];
      int kofs = (kt * 64 + lg * 16) ^ rswz;
#pragma unroll
      for (int rt = 0; rt < 8; ++rt)
        a[rt] = *(const s16x8*)(h1b + (rt * 16 + lr) * 256 + kofs);
      int ktg = p * 4 + kt;
#pragma unroll
      for (int ctl = 0; ctl < 2; ++ctl) {
        s16x8 bf = *(const s16x8*)(W2p + (((ktg * 16) + (w * 2 + ctl)) * 64 + l) * 8);
#pragma unroll
        for (int rt = 0; rt < 8; ++rt)
          acc[rt][ctl] = MFMA16(a[rt], bf, acc[rt][ctl]);
      }
    }
    __syncthreads();
  }

  // ---- epilogue: +b2, relu, reduce 16 edge rows per query (rt == query) ----
  float bias0 = b2[w * 32 + lr];
  float bias1 = b2[w * 32 + 16 + lr];
#pragma unroll
  for (int ctl = 0; ctl < 2; ++ctl) {
    int col = w * 32 + ctl * 16 + lr;
    float bias = ctl ? bias1 : bias0;
#pragma unroll
    for (int rt = 0; rt < 8; ++rt) {
      float s = fmaxf(acc[rt][ctl][0] + bias, 0.f)
              + fmaxf(acc[rt][ctl][1] + bias, 0.f)
              + fmaxf(acc[rt][ctl][2] + bias, 0.f)
              + fmaxf(acc[rt][ctl][3] + bias, 0.f);
      s += __shfl_xor(s, 16);
      s += __shfl_xor(s, 32);
      if (l < 16)
        *(unsigned short*)(gb + rt * 528 + col * 2) = f2bf_rne(s);
    }
  }
  __syncthreads();

  // ---- GEMM3: g[16x256] @ W3p; wave w -> out cols [w*16, w*16+16) ----
  f32x4 acc3 = zero4;
#pragma unroll
  for (int kt = 0; kt < 8; ++kt) {
    s16x8 a = *(const s16x8*)(gb + lr * 528 + kt * 64 + lg * 16);
    s16x8 bf = *(const s16x8*)(W3p + ((kt * 8 + w) * 64 + l) * 8);
    acc3 = MFMA16(a, bf, acc3);
  }
  int col = w * 16 + lr;
  if (lg < 2) {
    float tt = t3v[col], uu = u3v[col];
#pragma unroll
    for (int reg = 0; reg < 4; ++reg) {
      int q = lg * 4 + reg;
      out[(qbase + q) * Cc + col] = acc3[reg] + nvf[q] * tt - uu;
    }
  }
}

// ---------------------------------------------------------------------------
extern "C" void kernel_launch(void* const* d_in, const int* in_sizes, int n_in,
                              void* d_out, int out_size, void* d_ws, size_t ws_size,
                              hipStream_t stream) {
  // inputs: keys(0) points(1) feats(2) n_idxs(3) neighbor_valid(4)
  //         W1(5) b1(6) W2(7) b2(8) W3(9) b3(10)
  const float* feats = (const float*)d_in[2];
  const int* n_idxs = (const int*)d_in[3];
  const int* valid = (const int*)d_in[4];
  const float* W1 = (const float*)d_in[5];
  const float* b1 = (const float*)d_in[6];
  const float* W2 = (const float*)d_in[7];
  const float* b2 = (const float*)d_in[8];
  const float* W3 = (const float*)d_in[9];
  const float* b3 = (const float*)d_in[10];
  float* out = (float*)d_out;

  char* ws = (char*)d_ws;
  unsigned short* A_ws = (unsigned short*)(ws);                       // 8 MB
  unsigned short* B_ws = (unsigned short*)(ws + (8u << 20));          // 8 MB
  unsigned short* W1p  = (unsigned short*)(ws + (16u << 20));         // 128 KB
  unsigned short* W2p  = (unsigned short*)(ws + (16u << 20) + (128u << 10));  // 128 KB
  unsigned short* W3p  = (unsigned short*)(ws + (16u << 20) + (256u << 10));  // 64 KB
  float* t3v = (float*)(ws + (16u << 20) + (320u << 10));             // 512 B
  float* u3v = (float*)(ws + (16u << 20) + (321u << 10));             // 512 B

  pack_kernel<<<81, 256, 0, stream>>>(W1, W2, W3, b2, b3, W1p, W2p, W3p, t3v, u3v);
  k1_gemm<<<256, 256, 0, stream>>>(feats, W1p, b1, A_ws, B_ws);
  k2_fused<<<2048, 512, 0, stream>>>(A_ws, B_ws, W2p, W3p, n_idxs, valid, b2, t3v, u3v, out);
}